// Round 14
// baseline (1474.147 us; speedup 1.0000x reference)
//
#include <hip/hip_runtime.h>
#include <hip/hip_bf16.h>
#include <math.h>

#define LEAKY(x) ((x) > 0.0f ? (x) : 0.01f*(x))

typedef __attribute__((ext_vector_type(8))) short bfrag8;    // 8 bf16 in 4 VGPRs
typedef __attribute__((ext_vector_type(16))) float accv16;   // MFMA 32x32 accumulator

// round-to-nearest-even fp32 -> bf16 (as ushort)
__device__ __forceinline__ unsigned short bfr(float x) {
  unsigned int u = __float_as_uint(x);
  unsigned int r = u + 0x7fffu + ((u >> 16) & 1u);
  return (unsigned short)(r >> 16);
}

__device__ __forceinline__ unsigned int b2u(__hip_bfloat162 v) {
  union { __hip_bfloat162 b; unsigned int u; } x; x.b = v; return x.u;
}

// k-slot labeling for v_mfma_f32_32x32x16_bf16 A/B operands (any bijection works
// as long as A and B agree; sum over k is permutation-invariant).
#define KMAP(lh, j) (8*((j)>>2) + 4*(lh) + ((j)&3))

// ---------------- prep: W3 relayout + conv1 B-frags + conv2 B-frags ----------------
__global__ __launch_bounds__(256) void prep_weights(
    const float* __restrict__ W2, const float* __restrict__ W3,
    const float* __restrict__ W1,
    float* __restrict__ w3r, unsigned short* __restrict__ bfrag,
    unsigned short* __restrict__ bfrag2)
{
  int i = blockIdx.x*256 + threadIdx.x;
  if (i < 51200) {
    int co = i & 63; int k = i >> 6;
    w3r[k*64 + co] = W3[co*800 + k];
  }
  // conv1 B-frags: f = hl*10 + kwh*2 + ks ; lane: co=lane&15, p=(lane>>4)&1
  if (i < 1280) {
    int lane = i & 63;
    int f = i >> 6;                 // 0..19
    int hl = f / 10;
    int rem = f - hl*10;
    int kwh = rem >> 1;
    int ks  = rem & 1;
    int nn = lane & 31;
    int co = nn & 15, p = nn >> 4;
    int lh = (lane >> 5) & 1;
    #pragma unroll
    for (int j = 0; j < 8; ++j) {
      int k = ks*16 + KMAP(lh, j);
      float wv = 0.f;
      if (k < 27) {
        int ci = k / 9, kh = k - ci*9;
        int kw = 2*kwh + p;
        if (kw <= 8) wv = W1[((co*3 + ci)*9 + kh)*9 + kw];
      }
      unsigned short h = bfr(wv);
      unsigned short outv;
      if (hl == 0) outv = h;
      else {
        float hf = __uint_as_float(((unsigned int)h) << 16);
        outv = bfr(wv - hf);
      }
      bfrag[(f*64 + lane)*8 + j] = outv;
    }
  }
  // conv2 B-frags: flat ushort index i = (((kw*7+ks)*2+hl)*64+lane)*8 + j
  if (i < 50176) {
    int j = i & 7;
    int f = i >> 3;
    int lane = f & 63;
    int g = f >> 6;          // 0..97
    int hl = g & 1;
    int t2 = g >> 1;         // 0..48 = kw*7+ks
    int ks = t2 % 7, kw = t2 / 7;
    int co = lane & 31;
    int lh = (lane >> 5) & 1;
    int k = ks*16 + KMAP(lh, j);     // 0..111, always valid (K=112 exact)
    int ci = k / 7, kh = k - ci*7;
    float wv = W2[((co*16 + ci)*7 + kh)*7 + kw];
    unsigned short h = bfr(wv);
    if (hl == 0) bfrag2[i] = h;
    else {
      float hf = __uint_as_float(((unsigned int)h) << 16);
      bfrag2[i] = bfr(wv - hf);
    }
  }
}

// stage one A-plane slot t (0..831) for conv row r2 into (dsth,dstl).
// Identical math/numerics to the r12 staging body.
__device__ __forceinline__ void c1_stage(
    const float* __restrict__ Xn, int r2, int t,
    unsigned short* __restrict__ dsth, unsigned short* __restrict__ dstl)
{
  int q = t / 208;
  int c = t - q*208;
  int ks = q >> 1, lh = q & 1;
  int colX = c - 1;
  bool cok = (unsigned)colX < 200u;
  float xv[8];
  #pragma unroll
  for (int j = 0; j < 8; ++j) {
    int k = ks*16 + KMAP(lh, j);
    float x = 0.f;
    if (k < 27) {
      int ci = (k * 57) >> 9;          // k/9 for k<27
      int kh = k - ci*9;
      int row = r2 - 1 + kh;
      if (cok && (unsigned)row < 200u)
        x = Xn[(ci*200 + row)*200 + colX];
    }
    xv[j] = x;
  }
  unsigned int hh[4], ll[4];
  #pragma unroll
  for (int pq = 0; pq < 4; ++pq) {
    float x0 = xv[2*pq], x1 = xv[2*pq + 1];
    unsigned int h01 = b2u(__float22bfloat162_rn(make_float2(x0, x1)));
    float f0 = __uint_as_float(h01 << 16);
    float f1 = __uint_as_float(h01 & 0xffff0000u);
    unsigned int l01 = b2u(__float22bfloat162_rn(make_float2(x0 - f0, x1 - f1)));
    hh[pq] = h01; ll[pq] = l01;
  }
  *(uint4*)&dsth[(q*208 + c)*8] = make_uint4(hh[0], hh[1], hh[2], hh[3]);
  *(uint4*)&dstl[(q*208 + c)*8] = make_uint4(ll[0], ll[1], ll[2], ll[3]);
}

// ---------------- conv1 (3->16, 9x9, pad 1) + maxpool 7/5 + leaky via MFMA ----------------
// r12 structure (645us) + producer/consumer split: wave 7 stages ph+1 into the
// alternate plane buffer while waves 0-6 MFMA ph. Double-buffered planes;
// staging loop unroll(1) keeps VGPR at 64 (the r8/r10/r11/r13 cliff guard).
__global__ __launch_bounds__(512, 2) void conv1_mfma(
    const float* __restrict__ X, const float* __restrict__ b1,
    const unsigned short* __restrict__ bfrag, float* __restrict__ out1)
{
  const int pr = blockIdx.x;
  const int n  = blockIdx.y;
  const int tid = threadIdx.x;
  const int lane = tid & 63;
  const int w = tid >> 6;

  __shared__ __align__(16) unsigned short plh[2][4*208*8];   // 2 x 13312 B
  __shared__ __align__(16) unsigned short pll[2][4*208*8];   // 2 x 13312 B
  __shared__ float rowbuf[193][2][16];
  __shared__ float pm[38][17];

  bfrag8 Bf[20];
  #pragma unroll
  for (int f = 0; f < 20; ++f)
    Bf[f] = *(const bfrag8*)&bfrag[(f*64 + lane)*8];

  for (int t = tid; t < 608; t += 512)
    pm[t >> 4][t & 15] = -INFINITY;

  const float* __restrict__ Xn = X + (size_t)n * 120000;

  // prologue: all threads stage ph=0 into buffer 0
  for (int t = tid; t < 832; t += 512)
    c1_stage(Xn, 5*pr, t, plh[0], pll[0]);
  __syncthreads();

  for (int ph = 0; ph < 7; ++ph) {
    const int cur = ph & 1;

    if (w < 7) {
      // ---- MFMA phase: wave w computes M-tile m0 = 32*w from buf[cur] ----
      const int m0 = w*32;
      const int lh = (lane >> 5) & 1;
      const int mi = lane & 31;
      accv16 C;
      #pragma unroll
      for (int e = 0; e < 16; ++e) C[e] = 0.f;

      #pragma unroll
      for (int ks = 0; ks < 2; ++ks) {
        #pragma unroll
        for (int kwh = 0; kwh < 5; ++kwh) {
          int col = m0 + mi + 2*kwh;
          col = col > 207 ? 207 : col;
          int bidx = ((ks*2 + lh)*208 + col)*8;
          bfrag8 ah = *(const bfrag8*)&plh[cur][bidx];
          bfrag8 al = *(const bfrag8*)&pll[cur][bidx];
          C = __builtin_amdgcn_mfma_f32_32x32x16_bf16(ah, Bf[kwh*2 + ks],      C, 0, 0, 0); // xh*wh
          C = __builtin_amdgcn_mfma_f32_32x32x16_bf16(ah, Bf[10 + kwh*2 + ks], C, 0, 0, 0); // xh*wl
          C = __builtin_amdgcn_mfma_f32_32x32x16_bf16(al, Bf[kwh*2 + ks],      C, 0, 0, 0); // xl*wh
        }
      }
      const int co = lane & 15, p = (lane >> 4) & 1;
      #pragma unroll
      for (int reg = 0; reg < 16; ++reg) {
        int m = m0 + (reg & 3) + 8*(reg >> 2) + 4*lh;
        if (m < 193) rowbuf[m][p][co] = C[reg];   // pool reads rows 0..192 only
      }
    } else if (ph < 6) {
      // ---- producer: wave 7 stages ph+1 into buf[cur^1] (13 slots/lane) ----
      #pragma unroll 1
      for (int i = 0; i < 13; ++i)
        c1_stage(Xn, 5*pr + ph + 1, lane + 64*i, plh[cur^1], pll[cur^1]);
    }
    __syncthreads();

    // ---- pool update: 304 (pc, co-pair) items ----
    for (int t = tid; t < 304; t += 512) {
      int c2 = t & 7, pc = t >> 3;
      int u0 = 5*pc;
      float s0 = -INFINITY, s1 = -INFINITY;
      #pragma unroll
      for (int pw = 0; pw < 7; ++pw) {
        const float* r0 = &rowbuf[u0+pw][0][c2*2];
        const float* r1 = &rowbuf[u0+pw+1][1][c2*2];
        float v0 = r0[0] + r1[0];
        float v1 = r0[1] + r1[1];
        s0 = fmaxf(s0, v0); s1 = fmaxf(s1, v1);
      }
      pm[pc][c2*2]   = fmaxf(pm[pc][c2*2],   s0);
      pm[pc][c2*2+1] = fmaxf(pm[pc][c2*2+1], s1);
    }
    __syncthreads();
  }

  for (int t = tid; t < 608; t += 512) {
    int co = t & 15, pc = t >> 4;
    float v = pm[pc][co] + b1[co];
    out1[((n*16 + co)*38 + pr)*38 + pc] = LEAKY(v);
  }
}

// ---------------- conv2 (16->32, 7x7, pad 0) + maxpool 5/3 + leaky via MFMA ----------------
__global__ __launch_bounds__(512, 1) void conv2_mfma(
    const float* __restrict__ in, const float* __restrict__ b2,
    const unsigned short* __restrict__ bfrag2, float* __restrict__ out2)
{
  const int py = blockIdx.x;   // 0..9
  const int n  = blockIdx.y;   // 0..239
  const int tid = threadIdx.x;
  const int lane = tid & 63;
  const int w = tid >> 6;

  __shared__ __align__(16) unsigned short p2h[7][2][200][8];   // 44800 B
  __shared__ __align__(16) unsigned short p2l[7][2][200][8];   // 44800 B
  __shared__ float rowbuf[224][32];                            // 28672 B

  for (int t = tid; t < 2800; t += 512) {
    int col = t % 200;
    int q   = t / 200;
    int ks  = q >> 1, lhh = q & 1;
    int ph  = col / 40;
    int c   = col - ph*40;
    bool cok = c < 38;
    int rbase = 3*py + ph;
    float xv[8];
    #pragma unroll
    for (int j = 0; j < 8; ++j) {
      int k = ks*16 + KMAP(lhh, j);
      int ci = k / 7;
      int kh = k - ci*7;
      xv[j] = cok ? in[((n*16 + ci)*38 + (rbase + kh))*38 + c] : 0.f;
    }
    unsigned int hh[4], ll[4];
    #pragma unroll
    for (int pq = 0; pq < 4; ++pq) {
      float x0 = xv[2*pq], x1 = xv[2*pq + 1];
      unsigned int h01 = b2u(__float22bfloat162_rn(make_float2(x0, x1)));
      float f0 = __uint_as_float(h01 << 16);
      float f1 = __uint_as_float(h01 & 0xffff0000u);
      unsigned int l01 = b2u(__float22bfloat162_rn(make_float2(x0 - f0, x1 - f1)));
      hh[pq] = h01; ll[pq] = l01;
    }
    *(uint4*)&p2h[ks][lhh][col][0] = make_uint4(hh[0], hh[1], hh[2], hh[3]);
    *(uint4*)&p2l[ks][lhh][col][0] = make_uint4(ll[0], ll[1], ll[2], ll[3]);
  }
  __syncthreads();

  if (w < 7) {
    const int m0 = w*32;
    const int lh = (lane >> 5) & 1;
    const int mi = lane & 31;
    accv16 C;
    #pragma unroll
    for (int e = 0; e < 16; ++e) C[e] = 0.f;

    for (int ks = 0; ks < 7; ++ks) {
      bfrag8 Bh[7], Bl[7];
      #pragma unroll
      for (int kw = 0; kw < 7; ++kw) {
        int t2 = kw*7 + ks;
        Bh[kw] = *(const bfrag8*)&bfrag2[((t2*2 + 0)*64 + lane)*8];
        Bl[kw] = *(const bfrag8*)&bfrag2[((t2*2 + 1)*64 + lane)*8];
      }
      #pragma unroll
      for (int kw = 0; kw < 7; ++kw) {
        int col = m0 + mi + kw;
        col = col > 199 ? 199 : col;
        bfrag8 ah = *(const bfrag8*)&p2h[ks][lh][col][0];
        bfrag8 al = *(const bfrag8*)&p2l[ks][lh][col][0];
        C = __builtin_amdgcn_mfma_f32_32x32x16_bf16(ah, Bh[kw], C, 0, 0, 0);
        C = __builtin_amdgcn_mfma_f32_32x32x16_bf16(ah, Bl[kw], C, 0, 0, 0);
        C = __builtin_amdgcn_mfma_f32_32x32x16_bf16(al, Bh[kw], C, 0, 0, 0);
      }
    }
    const int co = lane & 31;
    #pragma unroll
    for (int reg = 0; reg < 16; ++reg) {
      int m = m0 + (reg & 3) + 8*(reg >> 2) + 4*((lane >> 5) & 1);
      rowbuf[m][co] = C[reg];
    }
  }
  __syncthreads();

  for (int t = tid; t < 320; t += 512) {
    int co = t & 31, pc = t >> 5;
    float m = -INFINITY;
    #pragma unroll
    for (int ph = 0; ph < 5; ++ph)
      #pragma unroll
      for (int pw = 0; pw < 5; ++pw)
        m = fmaxf(m, rowbuf[ph*40 + 3*pc + pw][co]);
    float v = m + b2[co];
    out2[((n*32 + co)*10 + py)*10 + pc] = LEAKY(v);
  }
}

// ---------------- conv3 (32->64, 5x5, pad 0) + maxpool 3/2 + leaky ----------------
__global__ __launch_bounds__(256) void conv3_pool(
    const float* __restrict__ in, const float* __restrict__ w3r,
    const float* __restrict__ b3, float* __restrict__ out3)
{
  const int n = blockIdx.x;
  __shared__ float sIn[3200];
  const int tid = threadIdx.x;
  for (int idx = tid; idx < 3200; idx += 256)
    sIn[idx] = in[n*3200 + idx];
  __syncthreads();
  const int co  = tid & 63;
  const int pos = tid >> 6;
  const int py = pos >> 1, px = pos & 1;
  float acc[3][3];
  float bv = b3[co];
  #pragma unroll
  for (int dy = 0; dy < 3; ++dy)
    #pragma unroll
    for (int dx = 0; dx < 3; ++dx) acc[dy][dx] = bv;
  for (int ci = 0; ci < 32; ++ci) {
    for (int kh = 0; kh < 5; ++kh) {
      float xr[3][7];
      #pragma unroll
      for (int dy = 0; dy < 3; ++dy)
        #pragma unroll
        for (int cc = 0; cc < 7; ++cc)
          xr[dy][cc] = sIn[ci*100 + (2*py + kh + dy)*10 + (2*px + cc)];
      #pragma unroll
      for (int kw = 0; kw < 5; ++kw) {
        float wv = w3r[(ci*25 + kh*5 + kw)*64 + co];
        #pragma unroll
        for (int dy = 0; dy < 3; ++dy)
          #pragma unroll
          for (int dx = 0; dx < 3; ++dx)
            acc[dy][dx] = fmaf(xr[dy][dx + kw], wv, acc[dy][dx]);
      }
    }
  }
  float m = -INFINITY;
  #pragma unroll
  for (int dy = 0; dy < 3; ++dy)
    #pragma unroll
    for (int dx = 0; dx < 3; ++dx) m = fmaxf(m, acc[dy][dx]);
  out3[n*256 + co*4 + py*2 + px] = LEAKY(m);
}

// ---------------- attention ----------------
__global__ __launch_bounds__(64) void attn_kernel(
    const float* __restrict__ Y, const float* __restrict__ Wq,
    const float* __restrict__ Wk, const float* __restrict__ Wv,
    float* __restrict__ Zc)
{
  const int h = blockIdx.x;
  const int b = blockIdx.y;
  __shared__ float sQ[30][2], sK[30][2], sV[30][4], sA[30][30];
  const int t = threadIdx.x;
  for (int it = t; it < 240; it += 64) {
    if (it < 60) {
      int s = it >> 1, q = it & 1;
      const float* yp = &Y[(b*30 + s)*256];
      const float* wp = &Wq[h*512 + q];
      float acc = 0.f;
      for (int e = 0; e < 256; ++e) acc += yp[e]*wp[e*2];
      sQ[s][q] = acc;
    } else if (it < 120) {
      int rr = it - 60;
      int s = rr >> 1, q = rr & 1;
      const float* yp = &Y[(b*30 + s)*256];
      const float* wp = &Wk[h*512 + q];
      float acc = 0.f;
      for (int e = 0; e < 256; ++e) acc += yp[e]*wp[e*2];
      sK[s][q] = acc;
    } else {
      int rr = it - 120;
      int s = rr >> 2, v = rr & 3;
      const float* yp = &Y[(b*30 + s)*256];
      const float* wp = &Wv[h*1024 + v];
      float acc = 0.f;
      for (int e = 0; e < 256; ++e) acc += yp[e]*wp[e*4];
      sV[s][v] = acc;
    }
  }
  __syncthreads();
  for (int it = t; it < 900; it += 64) {
    int si = it / 30, tj = it - si*30;
    sA[si][tj] = (sQ[si][0]*sK[tj][0] + sQ[si][1]*sK[tj][1]) * 0.70710678118654752f;
  }
  __syncthreads();
  if (t < 30) {
    float m = -INFINITY;
    for (int si = 0; si < 30; ++si) m = fmaxf(m, sA[si][t]);
    float sum = 0.f;
    for (int si = 0; si < 30; ++si) {
      float v = expf(sA[si][t] - m);
      sA[si][t] = v;
      sum += v;
    }
    float inv = 1.f/sum;
    for (int si = 0; si < 30; ++si) sA[si][t] *= inv;
  }
  __syncthreads();
  for (int it = t; it < 120; it += 64) {
    int si = it >> 2, v = it & 3;
    float z = 0.f;
    for (int tt = 0; tt < 30; ++tt) z += sA[si][tt]*sV[tt][v];
    Zc[(b*30 + si)*64 + h*4 + v] = z;
  }
}

// ---------------- final linear + softmax ----------------
__global__ __launch_bounds__(256) void head_kernel(
    const float* __restrict__ Zc, const float* __restrict__ Wr,
    const float* __restrict__ br, float* __restrict__ out)
{
  const int b = blockIdx.x;
  __shared__ float red[240];
  __shared__ float logit[10];
  const int t = threadIdx.x;
  if (t < 240) {
    int o = t / 24, j = t - o*24;
    const float* zp = &Zc[b*1920 + j*80];
    const float* wp = &Wr[o*1920 + j*80];
    float s = 0.f;
    for (int k = 0; k < 80; ++k) s += zp[k]*wp[k];
    red[t] = s;
  }
  __syncthreads();
  if (t < 10) {
    float s = br[t];
    #pragma unroll
    for (int j = 0; j < 24; ++j) s += red[t*24 + j];
    logit[t] = s;
  }
  __syncthreads();
  if (t == 0) {
    float m = -INFINITY;
    for (int o = 0; o < 10; ++o) m = fmaxf(m, logit[o]);
    float sum = 0.f;
    float ex[10];
    for (int o = 0; o < 10; ++o) { ex[o] = expf(logit[o] - m); sum += ex[o]; }
    float inv = 1.f/sum;
    for (int o = 0; o < 10; ++o) out[b*10 + o] = ex[o]*inv;
  }
}

extern "C" void kernel_launch(void* const* d_in, const int* in_sizes, int n_in,
                              void* d_out, int out_size, void* d_ws, size_t ws_size,
                              hipStream_t stream) {
  const float* X  = (const float*)d_in[0];
  const float* W1 = (const float*)d_in[1];
  const float* b1 = (const float*)d_in[2];
  const float* W2 = (const float*)d_in[3];
  const float* b2 = (const float*)d_in[4];
  const float* W3 = (const float*)d_in[5];
  const float* b3 = (const float*)d_in[6];
  const float* Wq = (const float*)d_in[7];
  const float* Wk = (const float*)d_in[8];
  const float* Wv = (const float*)d_in[9];
  const float* Wr = (const float*)d_in[10];
  const float* br = (const float*)d_in[11];

  float* ws  = (float*)d_ws;
  float* w3r = ws;                                          // 51200 floats
  unsigned short* bfrag  = (unsigned short*)(ws + 51200);   // 10240 ushort = 5120 floats
  unsigned short* bfrag2 = (unsigned short*)(ws + 56320);   // 50176 ushort = 25088 floats
  float* o1  = ws + 81408;                  // 240*16*38*38 = 5544960
  float* o2  = ws + 5626368;                // 240*32*10*10 = 768000
  float* o3  = ws + 6394368;                // 240*256      = 61440
  float* zc  = ws + 6455808;                // 8*30*64      = 15360

  prep_weights<<<dim3(200), dim3(256), 0, stream>>>(W2, W3, W1, w3r, bfrag, bfrag2);
  conv1_mfma  <<<dim3(38, 240), dim3(512), 0, stream>>>(X, b1, bfrag, o1);
  conv2_mfma  <<<dim3(10, 240), dim3(512), 0, stream>>>(o1, b2, bfrag2, o2);
  conv3_pool  <<<dim3(240),     dim3(256), 0, stream>>>(o2, w3r, b3, o3);
  attn_kernel <<<dim3(16, 8),   dim3(64),  0, stream>>>(o3, Wq, Wk, Wv, zc);
  head_kernel <<<dim3(8),       dim3(256), 0, stream>>>(zc, Wr, br, (float*)d_out);
}

// Round 15
// 746.523 us; speedup vs baseline: 1.9747x; 1.9747x over previous
//
#include <hip/hip_runtime.h>
#include <hip/hip_bf16.h>
#include <math.h>

#define LEAKY(x) ((x) > 0.0f ? (x) : 0.01f*(x))

typedef __attribute__((ext_vector_type(8))) short bfrag8;    // 8 bf16 in 4 VGPRs
typedef __attribute__((ext_vector_type(16))) float accv16;   // MFMA 32x32 accumulator

// round-to-nearest-even fp32 -> bf16 (as ushort)
__device__ __forceinline__ unsigned short bfr(float x) {
  unsigned int u = __float_as_uint(x);
  unsigned int r = u + 0x7fffu + ((u >> 16) & 1u);
  return (unsigned short)(r >> 16);
}

__device__ __forceinline__ unsigned int b2u(__hip_bfloat162 v) {
  union { __hip_bfloat162 b; unsigned int u; } x; x.b = v; return x.u;
}

// k-slot labeling for v_mfma_f32_32x32x16_bf16 A/B operands (any bijection works
// as long as A and B agree; sum over k is permutation-invariant).
#define KMAP(lh, j) (8*((j)>>2) + 4*(lh) + ((j)&3))

// ---------------- prep: W3 relayout + conv1 B-frags + conv2 B-frags ----------------
__global__ __launch_bounds__(256) void prep_weights(
    const float* __restrict__ W2, const float* __restrict__ W3,
    const float* __restrict__ W1,
    float* __restrict__ w3r, unsigned short* __restrict__ bfrag,
    unsigned short* __restrict__ bfrag2)
{
  int i = blockIdx.x*256 + threadIdx.x;
  if (i < 51200) {
    int co = i & 63; int k = i >> 6;
    w3r[k*64 + co] = W3[co*800 + k];
  }
  // conv1 B-frags: f = hl*10 + kwh*2 + ks ; lane: co=lane&15, p=(lane>>4)&1
  if (i < 1280) {
    int lane = i & 63;
    int f = i >> 6;                 // 0..19
    int hl = f / 10;
    int rem = f - hl*10;
    int kwh = rem >> 1;
    int ks  = rem & 1;
    int nn = lane & 31;
    int co = nn & 15, p = nn >> 4;
    int lh = (lane >> 5) & 1;
    #pragma unroll
    for (int j = 0; j < 8; ++j) {
      int k = ks*16 + KMAP(lh, j);
      float wv = 0.f;
      if (k < 27) {
        int ci = k / 9, kh = k - ci*9;
        int kw = 2*kwh + p;
        if (kw <= 8) wv = W1[((co*3 + ci)*9 + kh)*9 + kw];
      }
      unsigned short h = bfr(wv);
      unsigned short outv;
      if (hl == 0) outv = h;
      else {
        float hf = __uint_as_float(((unsigned int)h) << 16);
        outv = bfr(wv - hf);
      }
      bfrag[(f*64 + lane)*8 + j] = outv;
    }
  }
  // conv2 B-frags: flat ushort index i = (((kw*7+ks)*2+hl)*64+lane)*8 + j
  if (i < 50176) {
    int j = i & 7;
    int f = i >> 3;
    int lane = f & 63;
    int g = f >> 6;          // 0..97
    int hl = g & 1;
    int t2 = g >> 1;         // 0..48 = kw*7+ks
    int ks = t2 % 7, kw = t2 / 7;
    int co = lane & 31;
    int lh = (lane >> 5) & 1;
    int k = ks*16 + KMAP(lh, j);     // 0..111, always valid (K=112 exact)
    int ci = k / 7, kh = k - ci*7;
    float wv = W2[((co*16 + ci)*7 + kh)*7 + kw];
    unsigned short h = bfr(wv);
    if (hl == 0) bfrag2[i] = h;
    else {
      float hf = __uint_as_float(((unsigned int)h) << 16);
      bfrag2[i] = bfr(wv - hf);
    }
  }
}

// ---------------- conv1 (3->16, 9x9, pad 1) + maxpool 7/5 + leaky via MFMA ----------------
// r12 structure (645us, VGPR=64). Single change: barrier merge 3->2 per ph.
// Loop: {MFMA(ph); barrier; stage(ph+1) || pool(ph); barrier}. Staging code is
// byte-identical to r12 (no state held across MFMA -> VGPR stays 64).
__global__ __launch_bounds__(512, 2) void conv1_mfma(
    const float* __restrict__ X, const float* __restrict__ b1,
    const unsigned short* __restrict__ bfrag, float* __restrict__ out1)
{
  const int pr = blockIdx.x;
  const int n  = blockIdx.y;
  const int tid = threadIdx.x;
  const int lane = tid & 63;
  const int w = tid >> 6;

  __shared__ __align__(16) unsigned short plh[2][2][208][8];
  __shared__ __align__(16) unsigned short pll[2][2][208][8];
  __shared__ float rowbuf[193][2][16];
  __shared__ float pm[38][17];

  bfrag8 Bf[20];
  #pragma unroll
  for (int f = 0; f < 20; ++f)
    Bf[f] = *(const bfrag8*)&bfrag[(f*64 + lane)*8];

  for (int t = tid; t < 608; t += 512)
    pm[t >> 4][t & 15] = -INFINITY;

  const float* __restrict__ Xn = X + (size_t)n * 120000;

  // ---- staging body (identical numerics/code to r12), staged row = rr ----
#define C1_STAGE(RR) do {                                                  \
    const int r_ = (RR);                                                   \
    for (int t = tid; t < 832; t += 512) {                                 \
      int q = t / 208;                                                     \
      int c = t - q*208;                                                   \
      int ks = q >> 1, lh = q & 1;                                         \
      int colX = c - 1;                                                    \
      bool cok = (unsigned)colX < 200u;                                    \
      float xv[8];                                                         \
      _Pragma("unroll")                                                    \
      for (int j = 0; j < 8; ++j) {                                        \
        int k = ks*16 + KMAP(lh, j);                                       \
        float x = 0.f;                                                     \
        if (k < 27) {                                                      \
          int ci = (k * 57) >> 9;          /* k/9 for k<27 */              \
          int kh = k - ci*9;                                               \
          int row = r_ - 1 + kh;                                           \
          if (cok && (unsigned)row < 200u)                                 \
            x = Xn[(ci*200 + row)*200 + colX];                             \
        }                                                                  \
        xv[j] = x;                                                         \
      }                                                                    \
      unsigned int hh[4], ll[4];                                           \
      _Pragma("unroll")                                                    \
      for (int pq = 0; pq < 4; ++pq) {                                     \
        float x0 = xv[2*pq], x1 = xv[2*pq + 1];                            \
        unsigned int h01 = b2u(__float22bfloat162_rn(make_float2(x0, x1)));\
        float f0 = __uint_as_float(h01 << 16);                             \
        float f1 = __uint_as_float(h01 & 0xffff0000u);                     \
        unsigned int l01 = b2u(__float22bfloat162_rn(make_float2(x0 - f0, x1 - f1))); \
        hh[pq] = h01; ll[pq] = l01;                                        \
      }                                                                    \
      *(uint4*)&plh[ks][lh][c][0] = make_uint4(hh[0], hh[1], hh[2], hh[3]);\
      *(uint4*)&pll[ks][lh][c][0] = make_uint4(ll[0], ll[1], ll[2], ll[3]);\
    }                                                                      \
  } while (0)

  // prologue: stage ph=0
  C1_STAGE(5*pr);
  __syncthreads();

  for (int ph = 0; ph < 7; ++ph) {
    // ---- MFMA phase: wave w computes M-tile m0 = 32*w ----
    if (w < 7) {
      const int m0 = w*32;
      const int lh = (lane >> 5) & 1;
      const int mi = lane & 31;
      accv16 C;
      #pragma unroll
      for (int e = 0; e < 16; ++e) C[e] = 0.f;

      #pragma unroll
      for (int ks = 0; ks < 2; ++ks) {
        #pragma unroll
        for (int kwh = 0; kwh < 5; ++kwh) {
          int col = m0 + mi + 2*kwh;
          col = col > 207 ? 207 : col;
          bfrag8 ah = *(const bfrag8*)&plh[ks][lh][col][0];
          bfrag8 al = *(const bfrag8*)&pll[ks][lh][col][0];
          C = __builtin_amdgcn_mfma_f32_32x32x16_bf16(ah, Bf[kwh*2 + ks],      C, 0, 0, 0); // xh*wh
          C = __builtin_amdgcn_mfma_f32_32x32x16_bf16(ah, Bf[10 + kwh*2 + ks], C, 0, 0, 0); // xh*wl
          C = __builtin_amdgcn_mfma_f32_32x32x16_bf16(al, Bf[kwh*2 + ks],      C, 0, 0, 0); // xl*wh
        }
      }
      const int co = lane & 15, p = (lane >> 4) & 1;
      #pragma unroll
      for (int reg = 0; reg < 16; ++reg) {
        int m = m0 + (reg & 3) + 8*(reg >> 2) + 4*lh;
        if (m < 193) rowbuf[m][p][co] = C[reg];   // pool reads rows 0..192 only
      }
    }
    __syncthreads();

    // ---- merged phase: stage(ph+1) then pool(ph) ----
    if (ph < 6) C1_STAGE(5*pr + ph + 1);

    for (int t = tid; t < 304; t += 512) {
      int c2 = t & 7, pc = t >> 3;
      int u0 = 5*pc;
      float s0 = -INFINITY, s1 = -INFINITY;
      #pragma unroll
      for (int pw = 0; pw < 7; ++pw) {
        const float* r0 = &rowbuf[u0+pw][0][c2*2];
        const float* r1 = &rowbuf[u0+pw+1][1][c2*2];
        float v0 = r0[0] + r1[0];
        float v1 = r0[1] + r1[1];
        s0 = fmaxf(s0, v0); s1 = fmaxf(s1, v1);
      }
      pm[pc][c2*2]   = fmaxf(pm[pc][c2*2],   s0);
      pm[pc][c2*2+1] = fmaxf(pm[pc][c2*2+1], s1);
    }
    __syncthreads();
  }
#undef C1_STAGE

  for (int t = tid; t < 608; t += 512) {
    int co = t & 15, pc = t >> 4;
    float v = pm[pc][co] + b1[co];
    out1[((n*16 + co)*38 + pr)*38 + pc] = LEAKY(v);
  }
}

// ---------------- conv2 (16->32, 7x7, pad 0) + maxpool 5/3 + leaky via MFMA ----------------
__global__ __launch_bounds__(512, 1) void conv2_mfma(
    const float* __restrict__ in, const float* __restrict__ b2,
    const unsigned short* __restrict__ bfrag2, float* __restrict__ out2)
{
  const int py = blockIdx.x;   // 0..9
  const int n  = blockIdx.y;   // 0..239
  const int tid = threadIdx.x;
  const int lane = tid & 63;
  const int w = tid >> 6;

  __shared__ __align__(16) unsigned short p2h[7][2][200][8];   // 44800 B
  __shared__ __align__(16) unsigned short p2l[7][2][200][8];   // 44800 B
  __shared__ float rowbuf[224][32];                            // 28672 B

  for (int t = tid; t < 2800; t += 512) {
    int col = t % 200;
    int q   = t / 200;
    int ks  = q >> 1, lhh = q & 1;
    int ph  = col / 40;
    int c   = col - ph*40;
    bool cok = c < 38;
    int rbase = 3*py + ph;
    float xv[8];
    #pragma unroll
    for (int j = 0; j < 8; ++j) {
      int k = ks*16 + KMAP(lhh, j);
      int ci = k / 7;
      int kh = k - ci*7;
      xv[j] = cok ? in[((n*16 + ci)*38 + (rbase + kh))*38 + c] : 0.f;
    }
    unsigned int hh[4], ll[4];
    #pragma unroll
    for (int pq = 0; pq < 4; ++pq) {
      float x0 = xv[2*pq], x1 = xv[2*pq + 1];
      unsigned int h01 = b2u(__float22bfloat162_rn(make_float2(x0, x1)));
      float f0 = __uint_as_float(h01 << 16);
      float f1 = __uint_as_float(h01 & 0xffff0000u);
      unsigned int l01 = b2u(__float22bfloat162_rn(make_float2(x0 - f0, x1 - f1)));
      hh[pq] = h01; ll[pq] = l01;
    }
    *(uint4*)&p2h[ks][lhh][col][0] = make_uint4(hh[0], hh[1], hh[2], hh[3]);
    *(uint4*)&p2l[ks][lhh][col][0] = make_uint4(ll[0], ll[1], ll[2], ll[3]);
  }
  __syncthreads();

  if (w < 7) {
    const int m0 = w*32;
    const int lh = (lane >> 5) & 1;
    const int mi = lane & 31;
    accv16 C;
    #pragma unroll
    for (int e = 0; e < 16; ++e) C[e] = 0.f;

    for (int ks = 0; ks < 7; ++ks) {
      bfrag8 Bh[7], Bl[7];
      #pragma unroll
      for (int kw = 0; kw < 7; ++kw) {
        int t2 = kw*7 + ks;
        Bh[kw] = *(const bfrag8*)&bfrag2[((t2*2 + 0)*64 + lane)*8];
        Bl[kw] = *(const bfrag8*)&bfrag2[((t2*2 + 1)*64 + lane)*8];
      }
      #pragma unroll
      for (int kw = 0; kw < 7; ++kw) {
        int col = m0 + mi + kw;
        col = col > 199 ? 199 : col;
        bfrag8 ah = *(const bfrag8*)&p2h[ks][lh][col][0];
        bfrag8 al = *(const bfrag8*)&p2l[ks][lh][col][0];
        C = __builtin_amdgcn_mfma_f32_32x32x16_bf16(ah, Bh[kw], C, 0, 0, 0);
        C = __builtin_amdgcn_mfma_f32_32x32x16_bf16(ah, Bl[kw], C, 0, 0, 0);
        C = __builtin_amdgcn_mfma_f32_32x32x16_bf16(al, Bh[kw], C, 0, 0, 0);
      }
    }
    const int co = lane & 31;
    #pragma unroll
    for (int reg = 0; reg < 16; ++reg) {
      int m = m0 + (reg & 3) + 8*(reg >> 2) + 4*((lane >> 5) & 1);
      rowbuf[m][co] = C[reg];
    }
  }
  __syncthreads();

  for (int t = tid; t < 320; t += 512) {
    int co = t & 31, pc = t >> 5;
    float m = -INFINITY;
    #pragma unroll
    for (int ph = 0; ph < 5; ++ph)
      #pragma unroll
      for (int pw = 0; pw < 5; ++pw)
        m = fmaxf(m, rowbuf[ph*40 + 3*pc + pw][co]);
    float v = m + b2[co];
    out2[((n*32 + co)*10 + py)*10 + pc] = LEAKY(v);
  }
}

// ---------------- conv3 (32->64, 5x5, pad 0) + maxpool 3/2 + leaky ----------------
__global__ __launch_bounds__(256) void conv3_pool(
    const float* __restrict__ in, const float* __restrict__ w3r,
    const float* __restrict__ b3, float* __restrict__ out3)
{
  const int n = blockIdx.x;
  __shared__ float sIn[3200];
  const int tid = threadIdx.x;
  for (int idx = tid; idx < 3200; idx += 256)
    sIn[idx] = in[n*3200 + idx];
  __syncthreads();
  const int co  = tid & 63;
  const int pos = tid >> 6;
  const int py = pos >> 1, px = pos & 1;
  float acc[3][3];
  float bv = b3[co];
  #pragma unroll
  for (int dy = 0; dy < 3; ++dy)
    #pragma unroll
    for (int dx = 0; dx < 3; ++dx) acc[dy][dx] = bv;
  for (int ci = 0; ci < 32; ++ci) {
    for (int kh = 0; kh < 5; ++kh) {
      float xr[3][7];
      #pragma unroll
      for (int dy = 0; dy < 3; ++dy)
        #pragma unroll
        for (int cc = 0; cc < 7; ++cc)
          xr[dy][cc] = sIn[ci*100 + (2*py + kh + dy)*10 + (2*px + cc)];
      #pragma unroll
      for (int kw = 0; kw < 5; ++kw) {
        float wv = w3r[(ci*25 + kh*5 + kw)*64 + co];
        #pragma unroll
        for (int dy = 0; dy < 3; ++dy)
          #pragma unroll
          for (int dx = 0; dx < 3; ++dx)
            acc[dy][dx] = fmaf(xr[dy][dx + kw], wv, acc[dy][dx]);
      }
    }
  }
  float m = -INFINITY;
  #pragma unroll
  for (int dy = 0; dy < 3; ++dy)
    #pragma unroll
    for (int dx = 0; dx < 3; ++dx) m = fmaxf(m, acc[dy][dx]);
  out3[n*256 + co*4 + py*2 + px] = LEAKY(m);
}

// ---------------- attention ----------------
__global__ __launch_bounds__(64) void attn_kernel(
    const float* __restrict__ Y, const float* __restrict__ Wq,
    const float* __restrict__ Wk, const float* __restrict__ Wv,
    float* __restrict__ Zc)
{
  const int h = blockIdx.x;
  const int b = blockIdx.y;
  __shared__ float sQ[30][2], sK[30][2], sV[30][4], sA[30][30];
  const int t = threadIdx.x;
  for (int it = t; it < 240; it += 64) {
    if (it < 60) {
      int s = it >> 1, q = it & 1;
      const float* yp = &Y[(b*30 + s)*256];
      const float* wp = &Wq[h*512 + q];
      float acc = 0.f;
      for (int e = 0; e < 256; ++e) acc += yp[e]*wp[e*2];
      sQ[s][q] = acc;
    } else if (it < 120) {
      int rr = it - 60;
      int s = rr >> 1, q = rr & 1;
      const float* yp = &Y[(b*30 + s)*256];
      const float* wp = &Wk[h*512 + q];
      float acc = 0.f;
      for (int e = 0; e < 256; ++e) acc += yp[e]*wp[e*2];
      sK[s][q] = acc;
    } else {
      int rr = it - 120;
      int s = rr >> 2, v = rr & 3;
      const float* yp = &Y[(b*30 + s)*256];
      const float* wp = &Wv[h*1024 + v];
      float acc = 0.f;
      for (int e = 0; e < 256; ++e) acc += yp[e]*wp[e*4];
      sV[s][v] = acc;
    }
  }
  __syncthreads();
  for (int it = t; it < 900; it += 64) {
    int si = it / 30, tj = it - si*30;
    sA[si][tj] = (sQ[si][0]*sK[tj][0] + sQ[si][1]*sK[tj][1]) * 0.70710678118654752f;
  }
  __syncthreads();
  if (t < 30) {
    float m = -INFINITY;
    for (int si = 0; si < 30; ++si) m = fmaxf(m, sA[si][t]);
    float sum = 0.f;
    for (int si = 0; si < 30; ++si) {
      float v = expf(sA[si][t] - m);
      sA[si][t] = v;
      sum += v;
    }
    float inv = 1.f/sum;
    for (int si = 0; si < 30; ++si) sA[si][t] *= inv;
  }
  __syncthreads();
  for (int it = t; it < 120; it += 64) {
    int si = it >> 2, v = it & 3;
    float z = 0.f;
    for (int tt = 0; tt < 30; ++tt) z += sA[si][tt]*sV[tt][v];
    Zc[(b*30 + si)*64 + h*4 + v] = z;
  }
}

// ---------------- final linear + softmax ----------------
__global__ __launch_bounds__(256) void head_kernel(
    const float* __restrict__ Zc, const float* __restrict__ Wr,
    const float* __restrict__ br, float* __restrict__ out)
{
  const int b = blockIdx.x;
  __shared__ float red[240];
  __shared__ float logit[10];
  const int t = threadIdx.x;
  if (t < 240) {
    int o = t / 24, j = t - o*24;
    const float* zp = &Zc[b*1920 + j*80];
    const float* wp = &Wr[o*1920 + j*80];
    float s = 0.f;
    for (int k = 0; k < 80; ++k) s += zp[k]*wp[k];
    red[t] = s;
  }
  __syncthreads();
  if (t < 10) {
    float s = br[t];
    #pragma unroll
    for (int j = 0; j < 24; ++j) s += red[t*24 + j];
    logit[t] = s;
  }
  __syncthreads();
  if (t == 0) {
    float m = -INFINITY;
    for (int o = 0; o < 10; ++o) m = fmaxf(m, logit[o]);
    float sum = 0.f;
    float ex[10];
    for (int o = 0; o < 10; ++o) { ex[o] = expf(logit[o] - m); sum += ex[o]; }
    float inv = 1.f/sum;
    for (int o = 0; o < 10; ++o) out[b*10 + o] = ex[o]*inv;
  }
}

extern "C" void kernel_launch(void* const* d_in, const int* in_sizes, int n_in,
                              void* d_out, int out_size, void* d_ws, size_t ws_size,
                              hipStream_t stream) {
  const float* X  = (const float*)d_in[0];
  const float* W1 = (const float*)d_in[1];
  const float* b1 = (const float*)d_in[2];
  const float* W2 = (const float*)d_in[3];
  const float* b2 = (const float*)d_in[4];
  const float* W3 = (const float*)d_in[5];
  const float* b3 = (const float*)d_in[6];
  const float* Wq = (const float*)d_in[7];
  const float* Wk = (const float*)d_in[8];
  const float* Wv = (const float*)d_in[9];
  const float* Wr = (const float*)d_in[10];
  const float* br = (const float*)d_in[11];

  float* ws  = (float*)d_ws;
  float* w3r = ws;                                          // 51200 floats
  unsigned short* bfrag  = (unsigned short*)(ws + 51200);   // 10240 ushort = 5120 floats
  unsigned short* bfrag2 = (unsigned short*)(ws + 56320);   // 50176 ushort = 25088 floats
  float* o1  = ws + 81408;                  // 240*16*38*38 = 5544960
  float* o2  = ws + 5626368;                // 240*32*10*10 = 768000
  float* o3  = ws + 6394368;                // 240*256      = 61440
  float* zc  = ws + 6455808;                // 8*30*64      = 15360

  prep_weights<<<dim3(200), dim3(256), 0, stream>>>(W2, W3, W1, w3r, bfrag, bfrag2);
  conv1_mfma  <<<dim3(38, 240), dim3(512), 0, stream>>>(X, b1, bfrag, o1);
  conv2_mfma  <<<dim3(10, 240), dim3(512), 0, stream>>>(o1, b2, bfrag2, o2);
  conv3_pool  <<<dim3(240),     dim3(256), 0, stream>>>(o2, w3r, b3, o3);
  attn_kernel <<<dim3(16, 8),   dim3(64),  0, stream>>>(o3, Wq, Wk, Wv, zc);
  head_kernel <<<dim3(8),       dim3(256), 0, stream>>>(zc, Wr, br, (float*)d_out);
}

// Round 16
// 662.761 us; speedup vs baseline: 2.2243x; 1.1264x over previous
//
#include <hip/hip_runtime.h>
#include <hip/hip_bf16.h>
#include <math.h>

#define LEAKY(x) ((x) > 0.0f ? (x) : 0.01f*(x))

typedef __attribute__((ext_vector_type(8))) short bfrag8;    // 8 bf16 in 4 VGPRs
typedef __attribute__((ext_vector_type(16))) float accv16;   // MFMA 32x32 accumulator

// round-to-nearest-even fp32 -> bf16 (as ushort)
__device__ __forceinline__ unsigned short bfr(float x) {
  unsigned int u = __float_as_uint(x);
  unsigned int r = u + 0x7fffu + ((u >> 16) & 1u);
  return (unsigned short)(r >> 16);
}

__device__ __forceinline__ unsigned int b2u(__hip_bfloat162 v) {
  union { __hip_bfloat162 b; unsigned int u; } x; x.b = v; return x.u;
}

// k-slot labeling for v_mfma_f32_32x32x16_bf16 A/B operands (any bijection works
// as long as A and B agree; sum over k is permutation-invariant).
#define KMAP(lh, j) (8*((j)>>2) + 4*(lh) + ((j)&3))

// ---------------- prep: W3 relayout + conv1 B-frags + conv2 B-frags ----------------
__global__ __launch_bounds__(256) void prep_weights(
    const float* __restrict__ W2, const float* __restrict__ W3,
    const float* __restrict__ W1,
    float* __restrict__ w3r, unsigned short* __restrict__ bfrag,
    unsigned short* __restrict__ bfrag2)
{
  int i = blockIdx.x*256 + threadIdx.x;
  if (i < 51200) {
    int co = i & 63; int k = i >> 6;
    w3r[k*64 + co] = W3[co*800 + k];
  }
  // conv1 B-frags: f = hl*10 + kwh*2 + ks ; lane: co=lane&15, p=(lane>>4)&1
  if (i < 1280) {
    int lane = i & 63;
    int f = i >> 6;                 // 0..19
    int hl = f / 10;
    int rem = f - hl*10;
    int kwh = rem >> 1;
    int ks  = rem & 1;
    int nn = lane & 31;
    int co = nn & 15, p = nn >> 4;
    int lh = (lane >> 5) & 1;
    #pragma unroll
    for (int j = 0; j < 8; ++j) {
      int k = ks*16 + KMAP(lh, j);
      float wv = 0.f;
      if (k < 27) {
        int ci = k / 9, kh = k - ci*9;
        int kw = 2*kwh + p;
        if (kw <= 8) wv = W1[((co*3 + ci)*9 + kh)*9 + kw];
      }
      unsigned short h = bfr(wv);
      unsigned short outv;
      if (hl == 0) outv = h;
      else {
        float hf = __uint_as_float(((unsigned int)h) << 16);
        outv = bfr(wv - hf);
      }
      bfrag[(f*64 + lane)*8 + j] = outv;
    }
  }
  // conv2 B-frags: flat ushort index i = (((kw*7+ks)*2+hl)*64+lane)*8 + j
  if (i < 50176) {
    int j = i & 7;
    int f = i >> 3;
    int lane = f & 63;
    int g = f >> 6;          // 0..97
    int hl = g & 1;
    int t2 = g >> 1;         // 0..48 = kw*7+ks
    int ks = t2 % 7, kw = t2 / 7;
    int co = lane & 31;
    int lh = (lane >> 5) & 1;
    int k = ks*16 + KMAP(lh, j);     // 0..111, always valid (K=112 exact)
    int ci = k / 7, kh = k - ci*7;
    float wv = W2[((co*16 + ci)*7 + kh)*7 + kw];
    unsigned short h = bfr(wv);
    if (hl == 0) bfrag2[i] = h;
    else {
      float hf = __uint_as_float(((unsigned int)h) << 16);
      bfrag2[i] = bfr(wv - hf);
    }
  }
}

// ---------------- conv1 (3->16, 9x9, pad 1) + maxpool 7/5 + leaky via MFMA ----------------
// r15 structure (637us) + pair-block: each block computes TWO pooled rows
// (2*bx, 2*bx+1) over conv rows 10*bx+ph, ph=0..11. The 2 shared conv rows
// (ph=5,6) are staged+MFMA'd ONCE instead of twice -> -14% staging & MFMA.
// pmA accumulates ph 0..6, pmB ph 5..11. No state crosses MFMA (VGPR=64 law).
__global__ __launch_bounds__(512, 2) void conv1_mfma(
    const float* __restrict__ X, const float* __restrict__ b1,
    const unsigned short* __restrict__ bfrag, float* __restrict__ out1)
{
  const int bx = blockIdx.x;   // 0..18, pooled rows 2*bx and 2*bx+1
  const int n  = blockIdx.y;
  const int tid = threadIdx.x;
  const int lane = tid & 63;
  const int w = tid >> 6;

  __shared__ __align__(16) unsigned short plh[2][2][208][8];
  __shared__ __align__(16) unsigned short pll[2][2][208][8];
  __shared__ float rowbuf[193][2][16];
  __shared__ float pm[2][38][17];

  bfrag8 Bf[20];
  #pragma unroll
  for (int f = 0; f < 20; ++f)
    Bf[f] = *(const bfrag8*)&bfrag[(f*64 + lane)*8];

  for (int t = tid; t < 1216; t += 512)
    pm[t / 608][(t % 608) >> 4][t & 15] = -INFINITY;

  const float* __restrict__ Xn = X + (size_t)n * 120000;

  // ---- staging body (identical numerics to r12/r15), staged conv row = RR ----
#define C1_STAGE(RR) do {                                                  \
    const int r_ = (RR);                                                   \
    for (int t = tid; t < 832; t += 512) {                                 \
      int q = t / 208;                                                     \
      int c = t - q*208;                                                   \
      int ks = q >> 1, lh = q & 1;                                         \
      int colX = c - 1;                                                    \
      bool cok = (unsigned)colX < 200u;                                    \
      float xv[8];                                                         \
      _Pragma("unroll")                                                    \
      for (int j = 0; j < 8; ++j) {                                        \
        int k = ks*16 + KMAP(lh, j);                                       \
        float x = 0.f;                                                     \
        if (k < 27) {                                                      \
          int ci = (k * 57) >> 9;          /* k/9 for k<27 */              \
          int kh = k - ci*9;                                               \
          int row = r_ - 1 + kh;                                           \
          if (cok && (unsigned)row < 200u)                                 \
            x = Xn[(ci*200 + row)*200 + colX];                             \
        }                                                                  \
        xv[j] = x;                                                         \
      }                                                                    \
      unsigned int hh[4], ll[4];                                           \
      _Pragma("unroll")                                                    \
      for (int pq = 0; pq < 4; ++pq) {                                     \
        float x0 = xv[2*pq], x1 = xv[2*pq + 1];                            \
        unsigned int h01 = b2u(__float22bfloat162_rn(make_float2(x0, x1)));\
        float f0 = __uint_as_float(h01 << 16);                             \
        float f1 = __uint_as_float(h01 & 0xffff0000u);                     \
        unsigned int l01 = b2u(__float22bfloat162_rn(make_float2(x0 - f0, x1 - f1))); \
        hh[pq] = h01; ll[pq] = l01;                                        \
      }                                                                    \
      *(uint4*)&plh[ks][lh][c][0] = make_uint4(hh[0], hh[1], hh[2], hh[3]);\
      *(uint4*)&pll[ks][lh][c][0] = make_uint4(ll[0], ll[1], ll[2], ll[3]);\
    }                                                                      \
  } while (0)

  // prologue: stage ph=0 (conv row 10*bx)
  C1_STAGE(10*bx);
  __syncthreads();

  for (int ph = 0; ph < 12; ++ph) {
    // ---- MFMA phase: wave w computes M-tile m0 = 32*w ----
    if (w < 7) {
      const int m0 = w*32;
      const int lh = (lane >> 5) & 1;
      const int mi = lane & 31;
      accv16 C;
      #pragma unroll
      for (int e = 0; e < 16; ++e) C[e] = 0.f;

      #pragma unroll
      for (int ks = 0; ks < 2; ++ks) {
        #pragma unroll
        for (int kwh = 0; kwh < 5; ++kwh) {
          int col = m0 + mi + 2*kwh;
          col = col > 207 ? 207 : col;
          bfrag8 ah = *(const bfrag8*)&plh[ks][lh][col][0];
          bfrag8 al = *(const bfrag8*)&pll[ks][lh][col][0];
          C = __builtin_amdgcn_mfma_f32_32x32x16_bf16(ah, Bf[kwh*2 + ks],      C, 0, 0, 0); // xh*wh
          C = __builtin_amdgcn_mfma_f32_32x32x16_bf16(ah, Bf[10 + kwh*2 + ks], C, 0, 0, 0); // xh*wl
          C = __builtin_amdgcn_mfma_f32_32x32x16_bf16(al, Bf[kwh*2 + ks],      C, 0, 0, 0); // xl*wh
        }
      }
      const int co = lane & 15, p = (lane >> 4) & 1;
      #pragma unroll
      for (int reg = 0; reg < 16; ++reg) {
        int m = m0 + (reg & 3) + 8*(reg >> 2) + 4*lh;
        if (m < 193) rowbuf[m][p][co] = C[reg];   // pool reads rows 0..192 only
      }
    }
    __syncthreads();

    // ---- merged phase: stage(ph+1) then pool(ph) into pmA / pmB ----
    if (ph < 11) C1_STAGE(10*bx + ph + 1);

    for (int t = tid; t < 304; t += 512) {
      int c2 = t & 7, pc = t >> 3;
      int u0 = 5*pc;
      float s0 = -INFINITY, s1 = -INFINITY;
      #pragma unroll
      for (int pw = 0; pw < 7; ++pw) {
        const float* r0 = &rowbuf[u0+pw][0][c2*2];
        const float* r1 = &rowbuf[u0+pw+1][1][c2*2];
        float v0 = r0[0] + r1[0];
        float v1 = r0[1] + r1[1];
        s0 = fmaxf(s0, v0); s1 = fmaxf(s1, v1);
      }
      if (ph <= 6) {
        pm[0][pc][c2*2]   = fmaxf(pm[0][pc][c2*2],   s0);
        pm[0][pc][c2*2+1] = fmaxf(pm[0][pc][c2*2+1], s1);
      }
      if (ph >= 5) {
        pm[1][pc][c2*2]   = fmaxf(pm[1][pc][c2*2],   s0);
        pm[1][pc][c2*2+1] = fmaxf(pm[1][pc][c2*2+1], s1);
      }
    }
    __syncthreads();
  }
#undef C1_STAGE

  for (int t = tid; t < 1216; t += 512) {
    int half = t / 608;
    int tt = t - half*608;
    int co = tt & 15, pc = tt >> 4;
    float v = pm[half][pc][co] + b1[co];
    out1[((n*16 + co)*38 + (2*bx + half))*38 + pc] = LEAKY(v);
  }
}

// ---------------- conv2 (16->32, 7x7, pad 0) + maxpool 5/3 + leaky via MFMA ----------------
__global__ __launch_bounds__(512, 1) void conv2_mfma(
    const float* __restrict__ in, const float* __restrict__ b2,
    const unsigned short* __restrict__ bfrag2, float* __restrict__ out2)
{
  const int py = blockIdx.x;   // 0..9
  const int n  = blockIdx.y;   // 0..239
  const int tid = threadIdx.x;
  const int lane = tid & 63;
  const int w = tid >> 6;

  __shared__ __align__(16) unsigned short p2h[7][2][200][8];   // 44800 B
  __shared__ __align__(16) unsigned short p2l[7][2][200][8];   // 44800 B
  __shared__ float rowbuf[224][32];                            // 28672 B

  for (int t = tid; t < 2800; t += 512) {
    int col = t % 200;
    int q   = t / 200;
    int ks  = q >> 1, lhh = q & 1;
    int ph  = col / 40;
    int c   = col - ph*40;
    bool cok = c < 38;
    int rbase = 3*py + ph;
    float xv[8];
    #pragma unroll
    for (int j = 0; j < 8; ++j) {
      int k = ks*16 + KMAP(lhh, j);
      int ci = k / 7;
      int kh = k - ci*7;
      xv[j] = cok ? in[((n*16 + ci)*38 + (rbase + kh))*38 + c] : 0.f;
    }
    unsigned int hh[4], ll[4];
    #pragma unroll
    for (int pq = 0; pq < 4; ++pq) {
      float x0 = xv[2*pq], x1 = xv[2*pq + 1];
      unsigned int h01 = b2u(__float22bfloat162_rn(make_float2(x0, x1)));
      float f0 = __uint_as_float(h01 << 16);
      float f1 = __uint_as_float(h01 & 0xffff0000u);
      unsigned int l01 = b2u(__float22bfloat162_rn(make_float2(x0 - f0, x1 - f1)));
      hh[pq] = h01; ll[pq] = l01;
    }
    *(uint4*)&p2h[ks][lhh][col][0] = make_uint4(hh[0], hh[1], hh[2], hh[3]);
    *(uint4*)&p2l[ks][lhh][col][0] = make_uint4(ll[0], ll[1], ll[2], ll[3]);
  }
  __syncthreads();

  if (w < 7) {
    const int m0 = w*32;
    const int lh = (lane >> 5) & 1;
    const int mi = lane & 31;
    accv16 C;
    #pragma unroll
    for (int e = 0; e < 16; ++e) C[e] = 0.f;

    for (int ks = 0; ks < 7; ++ks) {
      bfrag8 Bh[7], Bl[7];
      #pragma unroll
      for (int kw = 0; kw < 7; ++kw) {
        int t2 = kw*7 + ks;
        Bh[kw] = *(const bfrag8*)&bfrag2[((t2*2 + 0)*64 + lane)*8];
        Bl[kw] = *(const bfrag8*)&bfrag2[((t2*2 + 1)*64 + lane)*8];
      }
      #pragma unroll
      for (int kw = 0; kw < 7; ++kw) {
        int col = m0 + mi + kw;
        col = col > 199 ? 199 : col;
        bfrag8 ah = *(const bfrag8*)&p2h[ks][lh][col][0];
        bfrag8 al = *(const bfrag8*)&p2l[ks][lh][col][0];
        C = __builtin_amdgcn_mfma_f32_32x32x16_bf16(ah, Bh[kw], C, 0, 0, 0);
        C = __builtin_amdgcn_mfma_f32_32x32x16_bf16(ah, Bl[kw], C, 0, 0, 0);
        C = __builtin_amdgcn_mfma_f32_32x32x16_bf16(al, Bh[kw], C, 0, 0, 0);
      }
    }
    const int co = lane & 31;
    #pragma unroll
    for (int reg = 0; reg < 16; ++reg) {
      int m = m0 + (reg & 3) + 8*(reg >> 2) + 4*((lane >> 5) & 1);
      rowbuf[m][co] = C[reg];
    }
  }
  __syncthreads();

  for (int t = tid; t < 320; t += 512) {
    int co = t & 31, pc = t >> 5;
    float m = -INFINITY;
    #pragma unroll
    for (int ph = 0; ph < 5; ++ph)
      #pragma unroll
      for (int pw = 0; pw < 5; ++pw)
        m = fmaxf(m, rowbuf[ph*40 + 3*pc + pw][co]);
    float v = m + b2[co];
    out2[((n*32 + co)*10 + py)*10 + pc] = LEAKY(v);
  }
}

// ---------------- conv3 (32->64, 5x5, pad 0) + maxpool 3/2 + leaky ----------------
__global__ __launch_bounds__(256) void conv3_pool(
    const float* __restrict__ in, const float* __restrict__ w3r,
    const float* __restrict__ b3, float* __restrict__ out3)
{
  const int n = blockIdx.x;
  __shared__ float sIn[3200];
  const int tid = threadIdx.x;
  for (int idx = tid; idx < 3200; idx += 256)
    sIn[idx] = in[n*3200 + idx];
  __syncthreads();
  const int co  = tid & 63;
  const int pos = tid >> 6;
  const int py = pos >> 1, px = pos & 1;
  float acc[3][3];
  float bv = b3[co];
  #pragma unroll
  for (int dy = 0; dy < 3; ++dy)
    #pragma unroll
    for (int dx = 0; dx < 3; ++dx) acc[dy][dx] = bv;
  for (int ci = 0; ci < 32; ++ci) {
    for (int kh = 0; kh < 5; ++kh) {
      float xr[3][7];
      #pragma unroll
      for (int dy = 0; dy < 3; ++dy)
        #pragma unroll
        for (int cc = 0; cc < 7; ++cc)
          xr[dy][cc] = sIn[ci*100 + (2*py + kh + dy)*10 + (2*px + cc)];
      #pragma unroll
      for (int kw = 0; kw < 5; ++kw) {
        float wv = w3r[(ci*25 + kh*5 + kw)*64 + co];
        #pragma unroll
        for (int dy = 0; dy < 3; ++dy)
          #pragma unroll
          for (int dx = 0; dx < 3; ++dx)
            acc[dy][dx] = fmaf(xr[dy][dx + kw], wv, acc[dy][dx]);
      }
    }
  }
  float m = -INFINITY;
  #pragma unroll
  for (int dy = 0; dy < 3; ++dy)
    #pragma unroll
    for (int dx = 0; dx < 3; ++dx) m = fmaxf(m, acc[dy][dx]);
  out3[n*256 + co*4 + py*2 + px] = LEAKY(m);
}

// ---------------- attention ----------------
__global__ __launch_bounds__(64) void attn_kernel(
    const float* __restrict__ Y, const float* __restrict__ Wq,
    const float* __restrict__ Wk, const float* __restrict__ Wv,
    float* __restrict__ Zc)
{
  const int h = blockIdx.x;
  const int b = blockIdx.y;
  __shared__ float sQ[30][2], sK[30][2], sV[30][4], sA[30][30];
  const int t = threadIdx.x;
  for (int it = t; it < 240; it += 64) {
    if (it < 60) {
      int s = it >> 1, q = it & 1;
      const float* yp = &Y[(b*30 + s)*256];
      const float* wp = &Wq[h*512 + q];
      float acc = 0.f;
      for (int e = 0; e < 256; ++e) acc += yp[e]*wp[e*2];
      sQ[s][q] = acc;
    } else if (it < 120) {
      int rr = it - 60;
      int s = rr >> 1, q = rr & 1;
      const float* yp = &Y[(b*30 + s)*256];
      const float* wp = &Wk[h*512 + q];
      float acc = 0.f;
      for (int e = 0; e < 256; ++e) acc += yp[e]*wp[e*2];
      sK[s][q] = acc;
    } else {
      int rr = it - 120;
      int s = rr >> 2, v = rr & 3;
      const float* yp = &Y[(b*30 + s)*256];
      const float* wp = &Wv[h*1024 + v];
      float acc = 0.f;
      for (int e = 0; e < 256; ++e) acc += yp[e]*wp[e*4];
      sV[s][v] = acc;
    }
  }
  __syncthreads();
  for (int it = t; it < 900; it += 64) {
    int si = it / 30, tj = it - si*30;
    sA[si][tj] = (sQ[si][0]*sK[tj][0] + sQ[si][1]*sK[tj][1]) * 0.70710678118654752f;
  }
  __syncthreads();
  if (t < 30) {
    float m = -INFINITY;
    for (int si = 0; si < 30; ++si) m = fmaxf(m, sA[si][t]);
    float sum = 0.f;
    for (int si = 0; si < 30; ++si) {
      float v = expf(sA[si][t] - m);
      sA[si][t] = v;
      sum += v;
    }
    float inv = 1.f/sum;
    for (int si = 0; si < 30; ++si) sA[si][t] *= inv;
  }
  __syncthreads();
  for (int it = t; it < 120; it += 64) {
    int si = it >> 2, v = it & 3;
    float z = 0.f;
    for (int tt = 0; tt < 30; ++tt) z += sA[si][tt]*sV[tt][v];
    Zc[(b*30 + si)*64 + h*4 + v] = z;
  }
}

// ---------------- final linear + softmax ----------------
__global__ __launch_bounds__(256) void head_kernel(
    const float* __restrict__ Zc, const float* __restrict__ Wr,
    const float* __restrict__ br, float* __restrict__ out)
{
  const int b = blockIdx.x;
  __shared__ float red[240];
  __shared__ float logit[10];
  const int t = threadIdx.x;
  if (t < 240) {
    int o = t / 24, j = t - o*24;
    const float* zp = &Zc[b*1920 + j*80];
    const float* wp = &Wr[o*1920 + j*80];
    float s = 0.f;
    for (int k = 0; k < 80; ++k) s += zp[k]*wp[k];
    red[t] = s;
  }
  __syncthreads();
  if (t < 10) {
    float s = br[t];
    #pragma unroll
    for (int j = 0; j < 24; ++j) s += red[t*24 + j];
    logit[t] = s;
  }
  __syncthreads();
  if (t == 0) {
    float m = -INFINITY;
    for (int o = 0; o < 10; ++o) m = fmaxf(m, logit[o]);
    float sum = 0.f;
    float ex[10];
    for (int o = 0; o < 10; ++o) { ex[o] = expf(logit[o] - m); sum += ex[o]; }
    float inv = 1.f/sum;
    for (int o = 0; o < 10; ++o) out[b*10 + o] = ex[o]*inv;
  }
}

extern "C" void kernel_launch(void* const* d_in, const int* in_sizes, int n_in,
                              void* d_out, int out_size, void* d_ws, size_t ws_size,
                              hipStream_t stream) {
  const float* X  = (const float*)d_in[0];
  const float* W1 = (const float*)d_in[1];
  const float* b1 = (const float*)d_in[2];
  const float* W2 = (const float*)d_in[3];
  const float* b2 = (const float*)d_in[4];
  const float* W3 = (const float*)d_in[5];
  const float* b3 = (const float*)d_in[6];
  const float* Wq = (const float*)d_in[7];
  const float* Wk = (const float*)d_in[8];
  const float* Wv = (const float*)d_in[9];
  const float* Wr = (const float*)d_in[10];
  const float* br = (const float*)d_in[11];

  float* ws  = (float*)d_ws;
  float* w3r = ws;                                          // 51200 floats
  unsigned short* bfrag  = (unsigned short*)(ws + 51200);   // 10240 ushort = 5120 floats
  unsigned short* bfrag2 = (unsigned short*)(ws + 56320);   // 50176 ushort = 25088 floats
  float* o1  = ws + 81408;                  // 240*16*38*38 = 5544960
  float* o2  = ws + 5626368;                // 240*32*10*10 = 768000
  float* o3  = ws + 6394368;                // 240*256      = 61440
  float* zc  = ws + 6455808;                // 8*30*64      = 15360

  prep_weights<<<dim3(200), dim3(256), 0, stream>>>(W2, W3, W1, w3r, bfrag, bfrag2);
  conv1_mfma  <<<dim3(19, 240), dim3(512), 0, stream>>>(X, b1, bfrag, o1);
  conv2_mfma  <<<dim3(10, 240), dim3(512), 0, stream>>>(o1, b2, bfrag2, o2);
  conv3_pool  <<<dim3(240),     dim3(256), 0, stream>>>(o2, w3r, b3, o3);
  attn_kernel <<<dim3(16, 8),   dim3(64),  0, stream>>>(o3, Wq, Wk, Wv, zc);
  head_kernel <<<dim3(8),       dim3(256), 0, stream>>>(zc, Wr, br, (float*)d_out);
}